// Round 21
// baseline (377.100 us; speedup 1.0000x reference)
//
#include <hip/hip_runtime.h>
#include <hip/hip_bf16.h>
#include <stdint.h>

// out = x @ W'^T + bias, W' = FWHT(W rows)/sqrt(n)  (H symmetric, folded into W)
// x (4,2048,8192) f32 -> M=8192, K=8192 ; W (2048,8192) -> N=2048 ; out f32.
// R21: occupancy experiment -- 256x128 tile (grid 512) + ring-3 72KiB LDS =
// 2 blocks/CU (vs 1 for all prior 256x256 variants). Cross-block wave overlap
// should hide the barrier/fence stalls that pinned MfmaUtil at 53%.

#define M_TOTAL 8192
#define K_TOTAL 8192
#define N_TOTAL 2048
#define D_IN 8192

typedef __attribute__((ext_vector_type(8))) short short8;
typedef __attribute__((ext_vector_type(4))) float f32x4;

typedef __attribute__((address_space(1))) void void_g;
typedef __attribute__((address_space(3))) void void_l;
typedef __attribute__((address_space(3))) short lds_s3;

__device__ __forceinline__ short f2bf(float f) {
  __hip_bfloat16 h = __float2bfloat16(f);
  return *reinterpret_cast<short*>(&h);
}

// ---------------- kernel 1: fused prep (cvt_x || fwht_w, parity-interleaved) ----
__global__ __launch_bounds__(512) void prep_kernel(const float* __restrict__ x,
                                                   short* __restrict__ xb,
                                                   const float* __restrict__ W,
                                                   short* __restrict__ wh) {
  __shared__ float buf[D_IN];
  const int b = blockIdx.x;
  if ((b & 1) == 0) {
    const int cb = b >> 1;
    const long n = (long)M_TOTAL * K_TOTAL;
    const long stride = (long)2048 * 512 * 8;
    for (long i = ((long)cb * 512 + threadIdx.x) * 8; i < n; i += stride) {
      float4 v0 = *(const float4*)(x + i);
      float4 v1 = *(const float4*)(x + i + 4);
      short8 o;
      o[0] = f2bf(v0.x); o[1] = f2bf(v0.y); o[2] = f2bf(v0.z); o[3] = f2bf(v0.w);
      o[4] = f2bf(v1.x); o[5] = f2bf(v1.y); o[6] = f2bf(v1.z); o[7] = f2bf(v1.w);
      *(short8*)(xb + i) = o;
    }
  } else {
    const int row = b >> 1;
    const float* src = W + (long)row * D_IN;
    for (int i = threadIdx.x; i < D_IN / 4; i += blockDim.x)
      ((float4*)buf)[i] = ((const float4*)src)[i];
    for (int h = 1; h < D_IN; h <<= 1) {
      __syncthreads();
      for (int p = threadIdx.x; p < D_IN / 2; p += blockDim.x) {
        int i = ((p & ~(h - 1)) << 1) | (p & (h - 1));
        float a = buf[i], bb = buf[i + h];
        buf[i] = a + bb;
        buf[i + h] = a - bb;
      }
    }
    __syncthreads();
    const float s = 0.011048543456039806f; // 1/sqrt(8192)
    short* dst = wh + (long)row * D_IN;
    for (int i = threadIdx.x; i < D_IN; i += blockDim.x)
      dst[i] = f2bf(buf[i] * s);
  }
}

// ---------------- kernel 2: 256x128 tile, BK=32, ring-3, 2 blocks/CU ------------
// 8 waves = 4M x 2N (wave out 64x64, acc 4x4 f32x4 = 64 VGPR). LDS ring-3:
// buf = A[256x32] 16K + B[128x32] 8K = 24K; 3 bufs = 72KiB -> 2 blocks/CU.
// Layout (R10-verified, 0 conflicts): rows of 4 x 16B chunks, chunk s of row r
// stored at slot s ^ ((r>>1)&3); staging thread t -> linear chunk t, global
// source slot (t&3)^((t>>3)&3) -> coalesced 64B/row. Per tile: lgkm(2); 8 MFMA;
// stage S(t+2) (3 gld_lds); lgkm(0); 8 MFMA; {vmcnt(3); barrier} (validates
// buf t+1); preload next-tile frags (8 asm ds_read).
#define NKT 256 // K-tiles of 32

#define SBAR __builtin_amdgcn_sched_barrier(0)
#define BAR __builtin_amdgcn_s_barrier()
#define FEN3 do { SBAR; asm volatile("s_waitcnt vmcnt(3)"); BAR; } while (0)
#define FEN0 do { SBAR; asm volatile("s_waitcnt vmcnt(0)"); BAR; } while (0)
#define FNOP do { } while (0)

// stage K-tile into buf SB (A rows 0-127, A rows 128-255, B rows 0-127)
#define STAGE(SB, KOFF)                                                                           \
  __builtin_amdgcn_global_load_lds((void_g*)(aLo + (KOFF)),                                       \
                                   (void_l*)&lds[(SB) * 12288 + sdst], 16, 0, 0);                 \
  __builtin_amdgcn_global_load_lds((void_g*)(aHi + (KOFF)),                                       \
                                   (void_l*)&lds[(SB) * 12288 + 4096 + sdst], 16, 0, 0);          \
  __builtin_amdgcn_global_load_lds((void_g*)(bSrc + (KOFF)),                                      \
                                   (void_l*)&lds[(SB) * 12288 + 8192 + sdst], 16, 0, 0);

#define DSR(dst, ADDR, IMM)                                                                       \
  asm volatile("ds_read_b128 %0, %1 offset:%2" : "=v"(dst) : "v"(ADDR), "i"(IMM))

// preload all 8 frags of buf NB (bn first, then am -> entry lgkm(2) = bn+am0,1)
#define BB(NB) ((NB) < 2 ? bAdLo : bAdHi)
#define BI(NB) (((NB) < 2 ? (NB) : 0) * 24576)
#define PRELOAD(NB)                                                                               \
  DSR(bn[0], BB(NB), BI(NB) + 0);    DSR(bn[1], BB(NB), BI(NB) + 1024);                           \
  DSR(bn[2], BB(NB), BI(NB) + 2048); DSR(bn[3], BB(NB), BI(NB) + 3072);                           \
  DSR(am[0], aAdr, (NB) * 24576 + 0);    DSR(am[1], aAdr, (NB) * 24576 + 1024);                   \
  DSR(am[2], aAdr, (NB) * 24576 + 2048); DSR(am[3], aAdr, (NB) * 24576 + 3072);

#define MFQ(M2)                                                                                   \
  __builtin_amdgcn_s_setprio(1);                                                                  \
  _Pragma("unroll") for (int mi = 0; mi < 2; ++mi) {                                              \
    _Pragma("unroll") for (int nj = 0; nj < 4; ++nj)                                              \
        acc[(M2) + mi][nj] = __builtin_amdgcn_mfma_f32_16x16x32_bf16(                             \
            am[(M2) + mi], bn[nj], acc[(M2) + mi][nj], 0, 0, 0);                                  \
  }                                                                                               \
  __builtin_amdgcn_s_setprio(0);

// one K-tile on buf (implicit via preloaded frags). DOSTG: stage S into SB at
// KOFF. DOPRE: preload buf NB after fence. FEN: FEN3/FEN0/FNOP.
#define KT(DOSTG, SB, KOFF, DOPRE, NB, FEN)                                                       \
  {                                                                                               \
    asm volatile("s_waitcnt lgkmcnt(2)");                                                         \
    SBAR;                                                                                         \
    MFQ(0);                                                                                       \
    if (DOSTG) { STAGE(SB, KOFF); }                                                               \
    SBAR;                                                                                         \
    asm volatile("s_waitcnt lgkmcnt(0)");                                                         \
    SBAR;                                                                                         \
    MFQ(2);                                                                                       \
    FEN;                                                                                          \
    if (DOPRE) { PRELOAD(NB); }                                                                   \
    SBAR;                                                                                         \
  }

__global__ __launch_bounds__(512, 4) void gemm_kernel(const short* __restrict__ A,
                                                      const short* __restrict__ B,
                                                      const float* __restrict__ bias,
                                                      float* __restrict__ C) {
  __shared__ __attribute__((aligned(16))) short lds[36864]; // 72 KiB (ring-3)

  const int tid = threadIdx.x;
  const int l = tid & 63;
  const int w = tid >> 6;
  const int wm = w >> 1;  // 0..3 (M quarter: rows wm*64..)
  const int wn = w & 1;   // 0..1 (N half: cols wn*64..)

  // XCD-aware bijective swizzle (nwg = 512, 512 % 8 == 0)
  const int bid = blockIdx.x;
  const int swz = (bid & 7) * 64 + (bid >> 3);
  const int bm = swz >> 4;  // 0..31
  const int bn_ = swz & 15; // 0..15
  const long tileM = (long)bm * 256;
  const long tileN = (long)bn_ * 128;

  // fragment read bases (bytes): row = (l&15) within 16-row frag; k-chunk l>>4,
  // stored at slot ^ ((row>>1)&3) = slot ^ ((l>>1)&3). mi/nj step = +1024.
  const int kx = ((l >> 4) ^ ((l >> 1) & 3)) * 16; // bytes
  const unsigned ldsb = (unsigned)(uintptr_t)(lds_s3*)&lds[0];
  const unsigned aAdr = ldsb + (unsigned)((wm * 64 + (l & 15)) * 64 + kx);
  const unsigned bAdLo = ldsb + 16384u + (unsigned)((wn * 64 + (l & 15)) * 64 + kx);
  const unsigned bAdHi = bAdLo + 49152u; // buf 2

  // staging: thread t -> LDS chunk t (row t>>2, slot t&3); global source slot
  // (t&3)^((t>>3)&3)  [key = (row>>1)&3 = (t>>3)&3]
  const int sdst = tid * 8; // shorts
  const int srow = tid >> 2;
  const int sslot = ((tid & 3) ^ ((tid >> 3) & 3)) * 8; // shorts
  const short* aLo = A + (tileM + srow) * (long)K_TOTAL + sslot;
  const short* aHi = aLo + 128 * (long)K_TOTAL;
  const short* bSrc = B + (tileN + srow) * (long)K_TOTAL + sslot;

  f32x4 acc[4][4];
#pragma unroll
  for (int mi = 0; mi < 4; ++mi)
#pragma unroll
    for (int nj = 0; nj < 4; ++nj)
      acc[mi][nj] = (f32x4){0.f, 0.f, 0.f, 0.f};

  short8 am[4], bn[4];

  // prologue: stage S0->buf0, S1->buf1 (6 loads); vmcnt(3) drains S0; preload 0
  STAGE(0, 0);
  STAGE(1, 32);
  SBAR;
  asm volatile("s_waitcnt vmcnt(3)");
  BAR;
  PRELOAD(0);
  SBAR;

  // main: tiles 0..251 (84 x 3); tile t: buf t%3, stage S(t+2)->buf (t+2)%3,
  // preload buf (t+1)%3 after the fence that validates it
  for (int t3 = 0; t3 < 252; t3 += 3) {
    KT(true, 2, (t3 + 2) * 32, true, 1, FEN3);
    KT(true, 0, (t3 + 3) * 32, true, 2, FEN3);
    KT(true, 1, (t3 + 4) * 32, true, 0, FEN3);
  }
  // tiles 252 (buf0, stage S254->buf2), 253 (buf1, stage S255->buf0),
  // 254 (buf2, drain), 255 (buf0, compute only)
  KT(true, 2, 254 * 32, true, 1, FEN3);
  KT(true, 0, 255 * 32, true, 2, FEN3);
  KT(false, 0, 0, true, 0, FEN0);
  KT(false, 0, 0, false, 0, FNOP);

  // epilogue: C = acc + bias  (C/D map: col = l&15, row = (l>>4)*4 + reg)
  const int rb = (int)tileM + wm * 64 + (l >> 4) * 4;
  const int cb = (int)tileN + wn * 64 + (l & 15);
#pragma unroll
  for (int mi = 0; mi < 4; ++mi)
#pragma unroll
    for (int nj = 0; nj < 4; ++nj) {
      float bv = bias[cb + nj * 16];
      const int r0 = rb + mi * 16;
#pragma unroll
      for (int r = 0; r < 4; ++r)
        C[(long)(r0 + r) * N_TOTAL + cb + nj * 16] = acc[mi][nj][r] + bv;
    }
}

extern "C" void kernel_launch(void* const* d_in, const int* in_sizes, int n_in,
                              void* d_out, int out_size, void* d_ws, size_t ws_size,
                              hipStream_t stream) {
  const float* x = (const float*)d_in[0];
  const float* W = (const float*)d_in[1];
  const float* bias = (const float*)d_in[2];
  float* out = (float*)d_out;

  short* xb = (short*)d_ws;                                          // 134 MB
  short* wh = (short*)((char*)d_ws + (size_t)M_TOTAL * K_TOTAL * 2); // 33.5 MB

  prep_kernel<<<4096, 512, 0, stream>>>(x, xb, W, wh);

  const int grid = (M_TOTAL / 256) * (N_TOTAL / 128); // 32 * 16 = 512
  gemm_kernel<<<grid, 512, 0, stream>>>(xb, wh, bias, out);
}

// Round 22
// 305.854 us; speedup vs baseline: 1.2329x; 1.2329x over previous
//
#include <hip/hip_runtime.h>
#include <hip/hip_bf16.h>
#include <stdint.h>

// out = x @ W'^T + bias, W' = FWHT(W rows)/sqrt(n)  (H symmetric, folded into W)
// x (4,2048,8192) f32 -> M=8192, K=8192 ; W (2048,8192) -> N=2048 ; out f32.
// R22: REVERT to R20 (best: 306us). R21's 2-blocks/CU experiment regressed
// (FETCH 197->420MB from halved N-reuse; per-tile overhead doubled). Session
// optimum: 256x256 8-phase gemm (229us, 53% MfmaUtil, 0 conflicts) + fused
// parity-interleaved prep (cvt_x || fwht_w, ~76us).

#define M_TOTAL 8192
#define K_TOTAL 8192
#define N_TOTAL 2048
#define D_IN 8192

typedef __attribute__((ext_vector_type(8))) short short8;
typedef __attribute__((ext_vector_type(4))) float f32x4;

typedef __attribute__((address_space(1))) void void_g;
typedef __attribute__((address_space(3))) void void_l;
typedef __attribute__((address_space(3))) short lds_s3;

__device__ __forceinline__ short f2bf(float f) {
  __hip_bfloat16 h = __float2bfloat16(f);
  return *reinterpret_cast<short*>(&h);
}

// ---------------- kernel 1: fused prep (cvt_x || fwht_w, parity-interleaved) ----
__global__ __launch_bounds__(512) void prep_kernel(const float* __restrict__ x,
                                                   short* __restrict__ xb,
                                                   const float* __restrict__ W,
                                                   short* __restrict__ wh) {
  __shared__ float buf[D_IN];
  const int b = blockIdx.x;
  if ((b & 1) == 0) {
    // ---- cvt path (blocks 0,2,...,8190 -> 2048 workers x 512 threads) ----
    const int cb = b >> 1;
    const long n = (long)M_TOTAL * K_TOTAL;
    const long stride = (long)2048 * 512 * 8;
    for (long i = ((long)cb * 512 + threadIdx.x) * 8; i < n; i += stride) {
      float4 v0 = *(const float4*)(x + i);
      float4 v1 = *(const float4*)(x + i + 4);
      short8 o;
      o[0] = f2bf(v0.x); o[1] = f2bf(v0.y); o[2] = f2bf(v0.z); o[3] = f2bf(v0.w);
      o[4] = f2bf(v1.x); o[5] = f2bf(v1.y); o[6] = f2bf(v1.z); o[7] = f2bf(v1.w);
      *(short8*)(xb + i) = o;
    }
  } else {
    // ---- fwht path (blocks 1,3,...,4095 -> 2048 rows) ----
    const int row = b >> 1;
    const float* src = W + (long)row * D_IN;
    for (int i = threadIdx.x; i < D_IN / 4; i += blockDim.x)
      ((float4*)buf)[i] = ((const float4*)src)[i];
    for (int h = 1; h < D_IN; h <<= 1) {
      __syncthreads();
      for (int p = threadIdx.x; p < D_IN / 2; p += blockDim.x) {
        int i = ((p & ~(h - 1)) << 1) | (p & (h - 1));
        float a = buf[i], bb = buf[i + h];
        buf[i] = a + bb;
        buf[i + h] = a - bb;
      }
    }
    __syncthreads();
    const float s = 0.011048543456039806f; // 1/sqrt(8192)
    short* dst = wh + (long)row * D_IN;
    for (int i = threadIdx.x; i < D_IN; i += blockDim.x)
      dst[i] = f2bf(buf[i] * s);
  }
}

// ---------------- kernel 2: 256x256 8-phase GEMM, coalesced XOR-swizzled LDS ----
// 8-phase schedule (BK=64, 2-dbuf, per-phase barriers, vmcnt(4)/K-tile,
// lgkm(8) stagger) with coalesced staging. Halves = [128 rows][64 k] bf16
// row-major, 16B-chunk XOR swizzle: chunk c of row r stored at slot c ^ (r&7).
#define NT 128 // K-tiles of 64

#define ADST(D, H) (((D) * 2 + (H)) * 8192 + sdst)          // shorts
#define BDST(D, H) (32768 + ((D) * 2 + (H)) * 8192 + sdst)  // shorts

#define STG(DST, SRC, KOFF)                                                                       \
  __builtin_amdgcn_global_load_lds((void_g*)((SRC) + (KOFF)), (void_l*)&lds[DST], 16, 0, 0);      \
  __builtin_amdgcn_global_load_lds((void_g*)((SRC) + (KOFF) + 64 * (long)K_TOTAL),                \
                                   (void_l*)&lds[(DST) + 4096], 16, 0, 0);

#define DSR(dst, ADDR, IMM)                                                                       \
  asm volatile("ds_read_b128 %0, %1 offset:%2" : "=v"(dst) : "v"(ADDR), "i"(IMM))

#define RD_A4(D, MIB)                                                                             \
  DSR(am[0][0], aAd0, (D) * 32768 + ((MIB) + 0) * 2048);                                          \
  DSR(am[0][1], aAd1, (D) * 32768 + ((MIB) + 0) * 2048);                                          \
  DSR(am[1][0], aAd0, (D) * 32768 + ((MIB) + 1) * 2048);                                          \
  DSR(am[1][1], aAd1, (D) * 32768 + ((MIB) + 1) * 2048);                                          \
  DSR(am[2][0], aAd0, (D) * 32768 + ((MIB) + 2) * 2048);                                          \
  DSR(am[2][1], aAd1, (D) * 32768 + ((MIB) + 2) * 2048);                                          \
  DSR(am[3][0], aAd0, (D) * 32768 + ((MIB) + 3) * 2048);                                          \
  DSR(am[3][1], aAd1, (D) * 32768 + ((MIB) + 3) * 2048);

#define RD_B2(D, NJB)                                                                             \
  DSR(bn[(NJB) + 0][0], bAd0, (D) * 32768 + ((NJB) + 0) * 2048);                                  \
  DSR(bn[(NJB) + 0][1], bAd1, (D) * 32768 + ((NJB) + 0) * 2048);                                  \
  DSR(bn[(NJB) + 1][0], bAd0, (D) * 32768 + ((NJB) + 1) * 2048);                                  \
  DSR(bn[(NJB) + 1][1], bAd1, (D) * 32768 + ((NJB) + 1) * 2048);

#define MF(MIB, NJB)                                                                              \
  __builtin_amdgcn_s_setprio(1);                                                                  \
  _Pragma("unroll") for (int mi = 0; mi < 4; ++mi) {                                              \
    _Pragma("unroll") for (int nj = 0; nj < 2; ++nj) {                                            \
      _Pragma("unroll") for (int ks = 0; ks < 2; ++ks) acc[(MIB) + mi][(NJB) + nj] =              \
          __builtin_amdgcn_mfma_f32_16x16x32_bf16(am[mi][ks], bn[(NJB) + nj][ks],                 \
                                                  acc[(MIB) + mi][(NJB) + nj], 0, 0, 0);          \
    }                                                                                             \
  }                                                                                               \
  __builtin_amdgcn_s_setprio(0);

#define BAR __builtin_amdgcn_s_barrier()
#define SBAR __builtin_amdgcn_sched_barrier(0)
#define LG0 do { asm volatile("s_waitcnt lgkmcnt(0)"); SBAR; } while (0)

#define KTILE(D, STGA, KA, STGB, KB, FN, DOF, LB)                                                 \
  {                                                                                               \
    RD_B2(D, 0);                                                                                  \
    RD_A4(D, 0);                                                                                  \
    if (STGA) { STG(ADST(D ^ 1, 0), aSrc0, KA); }                                                 \
    asm volatile("s_waitcnt lgkmcnt(8)");                                                         \
    BAR;                                                                                          \
    LG0;                                                                                          \
    MF(0, 0);                                                                                     \
    BAR;                                                                                          \
    RD_B2(D, 2);                                                                                  \
    if (STGA) { STG(ADST(D ^ 1, 1), aSrc1, KA); }                                                 \
    BAR;                                                                                          \
    LG0;                                                                                          \
    MF(0, 2);                                                                                     \
    BAR;                                                                                          \
    RD_A4(D, 4);                                                                                  \
    if (STGB) { STG(BDST(D, 0), bSrc0, KB); }                                                     \
    BAR;                                                                                          \
    LG0;                                                                                          \
    MF(4, 0);                                                                                     \
    BAR;                                                                                          \
    if (STGB) { STG(BDST(D, 1), bSrc1, KB); }                                                     \
    BAR;                                                                                          \
    MF(4, 2);                                                                                     \
    if (DOF) { asm volatile("s_waitcnt vmcnt(" FN ")"); }                                         \
    if (LB) BAR;                                                                                  \
  }

__global__ __launch_bounds__(512, 2) void gemm_kernel(const short* __restrict__ A,
                                                      const short* __restrict__ B,
                                                      const float* __restrict__ bias,
                                                      float* __restrict__ C) {
  __shared__ __attribute__((aligned(16))) short lds[65536]; // 128 KiB

  const int tid = threadIdx.x;
  const int l = tid & 63;
  const int w = tid >> 6;
  const int wm = w >> 2;   // 0..1 (M half)
  const int wn = w & 3;    // 0..3 (N quarter)
  const int wh = wn >> 1;  // B half

  // XCD-aware bijective swizzle (nwg = 256)
  const int bid = blockIdx.x;
  const int swz = (bid & 7) * 32 + (bid >> 3);
  const int bm = swz >> 3;
  const int bn_ = swz & 7;
  const long tileM = (long)bm * 256;
  const long tileN = (long)bn_ * 256;

  // read bases (bytes): row-in-frag = l&15, slot0 = (l>>4) ^ (l&7); ks1 = ^64
  const int slot0 = (l >> 4) ^ (l & 7);
  const int laneb = (l & 15) * 128 + slot0 * 16;
  const unsigned ldsb = (unsigned)(uintptr_t)(lds_s3*)&lds[0];
  const unsigned aAd0 = ldsb + (unsigned)(wm * 16384 + laneb);
  const unsigned aAd1 = aAd0 ^ 64u;
  const unsigned bAd0 = ldsb + 65536u + (unsigned)(wh * 16384 + (wn & 1) * 8192 + laneb);
  const unsigned bAd1 = bAd0 ^ 64u;

  // staging: thread t -> LDS chunk t (row t>>3, slot t&7); global source chunk
  // (t&7)^((t>>3)&7) of row t>>3 (and +64 rows for the second load)
  const int sdst = tid * 8; // shorts
  const int srow = tid >> 3;
  const int sslot = ((tid & 7) ^ (srow & 7)) * 8; // shorts
  const short* aSrc0 = A + (tileM + srow) * (long)K_TOTAL + sslot;
  const short* aSrc1 = aSrc0 + 128 * (long)K_TOTAL;
  const short* bSrc0 = B + (tileN + srow) * (long)K_TOTAL + sslot;
  const short* bSrc1 = bSrc0 + 128 * (long)K_TOTAL;

  f32x4 acc[8][4];
#pragma unroll
  for (int mi = 0; mi < 8; ++mi)
#pragma unroll
    for (int nj = 0; nj < 4; ++nj)
      acc[mi][nj] = (f32x4){0.f, 0.f, 0.f, 0.f};

  // prologue: A(0)->d0, B(0)->d0, B(1)->d1 (12 loads); vmcnt(4) leaves B(1)
  STG(ADST(0, 0), aSrc0, 0);
  STG(ADST(0, 1), aSrc1, 0);
  STG(BDST(0, 0), bSrc0, 0);
  STG(BDST(0, 1), bSrc1, 0);
  STG(BDST(1, 0), bSrc0, 64);
  STG(BDST(1, 1), bSrc1, 64);
  asm volatile("s_waitcnt vmcnt(4)");
  BAR;

  short8 am[4][2], bn[4][2];

  // main: t = 0,2,...,124
  for (int t = 0; t < NT - 2; t += 2) {
    KTILE(0, true, (t + 1) * 64, true, (t + 2) * 64, "4", true, true);
    KTILE(1, true, (t + 2) * 64, true, (t + 3) * 64, "4", true, true);
  }
  // tail: t=126 stages A(127), drains; t=127 compute-only
  KTILE(0, true, 127 * 64, false, 0, "0", true, true);
  KTILE(1, false, 0, false, 0, "0", false, false);

  // epilogue: C = acc + bias  (C/D map: col = l&15, row = (l>>4)*4 + reg)
  const int rb = (int)tileM + wm * 128 + (l >> 4) * 4;
  const int cb = (int)tileN + wn * 64 + (l & 15);
#pragma unroll
  for (int mi = 0; mi < 8; ++mi)
#pragma unroll
    for (int nj = 0; nj < 4; ++nj) {
      float bv = bias[cb + nj * 16];
      const int r0 = rb + mi * 16;
#pragma unroll
      for (int r = 0; r < 4; ++r)
        C[(long)(r0 + r) * N_TOTAL + cb + nj * 16] = acc[mi][nj][r] + bv;
    }
}

extern "C" void kernel_launch(void* const* d_in, const int* in_sizes, int n_in,
                              void* d_out, int out_size, void* d_ws, size_t ws_size,
                              hipStream_t stream) {
  const float* x = (const float*)d_in[0];
  const float* W = (const float*)d_in[1];
  const float* bias = (const float*)d_in[2];
  float* out = (float*)d_out;

  short* xb = (short*)d_ws;                                          // 134 MB
  short* wh = (short*)((char*)d_ws + (size_t)M_TOTAL * K_TOTAL * 2); // 33.5 MB

  prep_kernel<<<4096, 512, 0, stream>>>(x, xb, W, wh);

  const int grid = (M_TOTAL / 256) * (N_TOTAL / 256); // 256
  gemm_kernel<<<grid, 512, 0, stream>>>(xb, wh, bias, out);
}